// Round 9
// baseline (172.877 us; speedup 1.0000x reference)
//
#include <hip/hip_runtime.h>
#include <hip/hip_bf16.h>
#include <math.h>

// Problem constants (BN, N, FIN, FO, H) from the reference
#define BN_   4
#define NN_   2048
#define FIN_  128
#define FO_   64
#define H_    4
#define D_    256   // FO*H

typedef __attribute__((ext_vector_type(8))) short bf16x8;   // 8 bf16 = 4 VGPRs
typedef __attribute__((ext_vector_type(4))) float floatx4;  // MFMA C/D frag

#define LOG2E 1.4426950408889634f

#if __has_builtin(__builtin_amdgcn_exp2f)
#define EXP2(x) __builtin_amdgcn_exp2f(x)
#else
#define EXP2(x) exp2f(x)
#endif

__device__ __forceinline__ float bf2f(short u) {
    union { unsigned int i; float f; } v;
    v.i = ((unsigned int)(unsigned short)u) << 16;
    return v.f;
}
__device__ __forceinline__ short f2bf(float f) {
    union { float f; unsigned int u; } v; v.f = f;
    unsigned int r = v.u + 0x7fffu + ((v.u >> 16) & 1u);  // RNE
    return (short)(unsigned short)(r >> 16);
}

// pack two floats to two bf16 (RNE) in one dword; elem0 in low 16 bits
#if defined(__BF16_MANT_DIG__)
typedef __bf16 bfr2 __attribute__((ext_vector_type(2)));
__device__ __forceinline__ unsigned int pack_bf16(float a, float b) {
    union { bfr2 h; unsigned int u; } v;
    v.h = (bfr2){(__bf16)a, (__bf16)b};
    return v.u;
}
#else
__device__ __forceinline__ unsigned int pack_bf16(float a, float b) {
    return ((unsigned int)(unsigned short)f2bf(a)) |
           (((unsigned int)(unsigned short)f2bf(b)) << 16);
}
#endif

// load 8 consecutive fp32 and round to a bf16x8 MFMA fragment
__device__ __forceinline__ bf16x8 load8f(const float* __restrict__ p) {
    floatx4 a = *(const floatx4*)p;
    floatx4 b = *(const floatx4*)(p + 4);
    union { bf16x8 v; unsigned int u[4]; } r;
    r.u[0] = pack_bf16(a[0], a[1]);
    r.u[1] = pack_bf16(a[2], a[3]);
    r.u[2] = pack_bf16(b[0], b[1]);
    r.u[3] = pack_bf16(b[2], b[3]);
    return r.v;
}

// attention score -> exp weight (bit-identical across rounds)
__device__ __forceinline__ float score_exp(float ssv, float stv, float av) {
    float s = ssv + stv;
    s = fmaxf(s, 0.2f * s);            // leaky_relu(0.2)
    return EXP2((s + av) * LOG2E);
}

// ---------------------------------------------------------------------------
// Kernel 1: projection -> PT2 (fragment-tiled bf16) + s_src/s_tgt.
// Round-9: ONE dispatch covers all 4 batches (grid z = BN). Batches z<nws
// write the ws slabs; z>=nws write the staging image (inside out[2..3],
// same contiguous layout as ws). Body is round-8's verified kernel
// (R2-shape main loop + LDS [64][264] transpose + dense contiguous store).
// PT2 layout (IDENTICAL to rounds 6-8):
//   elem(h, f, j) -> (h*64 + (j>>5))*2048 + (f>>4)*512 + ((j>>3)&3)*128
//                    + (f&15)*8 + (j&7)        [per-batch slab]
// ---------------------------------------------------------------------------
__global__ __launch_bounds__(256) void proj_kernel(
    const float* __restrict__ x,      // (BN, NN, FIN) fp32
    const float* __restrict__ wproj,  // (D, FIN) fp32
    const float* __restrict__ ssrc,   // (H, FO) fp32
    const float* __restrict__ stgt,   // (H, FO) fp32
    short* pt_ws,  float* sS_ws,  float* sT_ws,    // ws image (nws slabs)
    short* pt_st,  float* sS_st,  float* sT_st,    // staging image
    int b0, int nws)
{
    __shared__ short ptl[64][264];    // [f][j_local], +8 pad (33792 B)

    const int tid  = threadIdx.x;
    const int wave = tid >> 6;
    const int lane = tid & 63;
    const int l16  = lane & 15;
    const int quad = lane >> 4;

    const int z  = blockIdx.z;
    const int b  = b0 + z;
    const int h  = blockIdx.y;            // head
    const int j0 = blockIdx.x * 256 + wave * 64;

    short* ptd;  float* sSd;  float* sTd;  int brl;
    if (z < nws) { ptd = pt_ws; sSd = sS_ws; sTd = sT_ws; brl = z; }
    else         { ptd = pt_st; sSd = sS_st; sTd = sT_st; brl = z - nws; }

    floatx4 acc[4][4];
#pragma unroll
    for (int mi = 0; mi < 4; ++mi)
#pragma unroll
        for (int nj = 0; nj < 4; ++nj)
            acc[mi][nj] = (floatx4){0.f, 0.f, 0.f, 0.f};

#pragma unroll
    for (int kc = 0; kc < 4; ++kc) {
        const int c = kc * 32 + quad * 8;
        bf16x8 afr[4], bfr[4];
#pragma unroll
        for (int mi = 0; mi < 4; ++mi) {
            int f = mi * 16 + l16;                // f within head
            int srow = f * H_ + h;                // W_proj row (flat d = f*H+h)
            afr[mi] = load8f(wproj + srow * FIN_ + c);
        }
#pragma unroll
        for (int nj = 0; nj < 4; ++nj) {
            int j = j0 + nj * 16 + l16;
            bfr[nj] = load8f(x + ((size_t)b * NN_ + j) * FIN_ + c);
        }
#pragma unroll
        for (int mi = 0; mi < 4; ++mi)
#pragma unroll
            for (int nj = 0; nj < 4; ++nj)
                acc[mi][nj] = __builtin_amdgcn_mfma_f32_16x16x32_bf16(
                    afr[mi], bfr[nj], acc[mi][nj], 0, 0, 0);
    }

    // ---- stage C-fragments into the [f][j_local] LDS tile ----
    // lane holds (f = mi*16 + quad*4 + r, j_local = wave*64 + nj*16 + l16)
#pragma unroll
    for (int mi = 0; mi < 4; ++mi)
#pragma unroll
        for (int r = 0; r < 4; ++r)
#pragma unroll
            for (int nj = 0; nj < 4; ++nj)
                ptl[mi * 16 + quad * 4 + r][wave * 64 + nj * 16 + l16] =
                    f2bf(acc[mi][nj][r]);

    // ---- score dot-products from fp32 accumulators (register-local) ----
    float wsv[4][4], wtv[4][4];
#pragma unroll
    for (int mi = 0; mi < 4; ++mi)
#pragma unroll
        for (int r = 0; r < 4; ++r) {
            int f = mi * 16 + quad * 4 + r;
            wsv[mi][r] = ssrc[h * FO_ + f];
            wtv[mi][r] = stgt[h * FO_ + f];
        }
    const size_t sbase = ((size_t)brl * H_ + h) * NN_;
#pragma unroll
    for (int nj = 0; nj < 4; ++nj) {
        float ps = 0.f, pg = 0.f;
#pragma unroll
        for (int mi = 0; mi < 4; ++mi)
#pragma unroll
            for (int r = 0; r < 4; ++r) {
                ps = fmaf(wsv[mi][r], acc[mi][nj][r], ps);
                pg = fmaf(wtv[mi][r], acc[mi][nj][r], pg);
            }
        ps += __shfl_xor(ps, 16, 64); ps += __shfl_xor(ps, 32, 64);
        pg += __shfl_xor(pg, 16, 64); pg += __shfl_xor(pg, 32, 64);
        if (quad == 0) {
            int j = j0 + nj * 16 + l16;
            sSd[sbase + j] = ps;
            sTd[sbase + j] = pg;
        }
    }

    __syncthreads();

    // ---- dense PT2 store: block's 32 KB range is CONTIGUOUS in PT2 ----
    const size_t base = ((size_t)brl * H_ + h) * (size_t)(64 * 2048)
                      + (size_t)(blockIdx.x * 8) * 2048;
#pragma unroll
    for (int p = 0; p < 8; ++p) {
        const int uid  = p * 256 + tid;           // 0..2047
        const int tile = uid >> 8;                // == p (wave-uniform)
        const int mi   = (uid >> 6) & 3;          // == wave
        const int l    = uid & 63;                // == lane
        const int f    = mi * 16 + (l & 15);
        const int js   = tile * 32 + (l >> 4) * 8;
        bf16x8 v = *(const bf16x8*)&ptl[f][js];   // 16B-aligned (264|8, js|8)
        *(bf16x8*)&ptd[base + (size_t)uid * 8] = v;  // dense: lane*16B
    }
}

// ---------------------------------------------------------------------------
// Flat bit-exact copy (staging image -> ws image), float4 grid-stride.
// ---------------------------------------------------------------------------
__global__ __launch_bounds__(256) void copy_kernel(
    floatx4* __restrict__ dst, const floatx4* __restrict__ src, int n16)
{
    int i = blockIdx.x * 256 + threadIdx.x;
    const int stride = gridDim.x * 256;
    for (; i < n16; i += stride)
        dst[i] = src[i];
}

// ---------------------------------------------------------------------------
// Kernel 2: fused attention, 4 heads per block, i-tile = 16.
// UNCHANGED from rounds 6-8 (53.5 us, verified): all main-loop global loads
// dense; adj staged via wave-private LDS tile with T14 issue-early/
// write-late split; PT B-fragments read from PT2 as uniform_base + lane*16.
// ---------------------------------------------------------------------------
#define RSTRIDE 65   // LDS row stride (pad +1 col to break bank alignment)
#define WSLOT   (RSTRIDE * 16 + 16)   // 1056 floats per wave slot

__global__ __launch_bounds__(512, 2) void attn_kernel(
    const float* __restrict__ adj,    // (BN, NN, NN) fp32
    const short* __restrict__ pt,     // PT2 slabs (see proj_kernel)
    const float* __restrict__ sS,     // (nb*H, NN) fp32
    const float* __restrict__ sT,     // (nb*H, NN) fp32
    const float* __restrict__ bias,   // (D,) fp32
    float* __restrict__ out,          // (BN, NN, D) fp32
    int b0)
{
    __shared__ union {
        struct {
            float adjs[8][16][36];    // per-wave adj tile (18432 B)
            float st[8][4][256];      // per-wave s_tgt slices (32768 B)
        } m;
        float red[8][WSLOT];          // cross-wave reduction (33792 B)
    } sm;

    const int tid  = threadIdx.x;
    const int w    = tid >> 6;        // wave = 256-wide j-slice
    const int lane = tid & 63;
    const int l16  = lane & 15;
    const int quad = lane >> 4;
    const int r8   = lane >> 3;       // 0..7  (adj stage row-in-group)
    const int c4   = (lane & 7) * 4;  // 0,4..28 (adj stage col, floats)

    const int b_rel = blockIdx.z;
    const int b  = b0 + b_rel;
    const int i0 = blockIdx.x * 16;

    const short* pt2_b = pt + (size_t)b_rel * H_ * (size_t)(64 * 2048);
    const size_t sb = (size_t)b_rel * H_ * NN_;

    // stage s_tgt slices for all 4 heads (wave-private; no barrier needed)
    {
        const int t = lane * 4;
#pragma unroll
        for (int h = 0; h < 4; ++h)
            *(floatx4*)&sm.m.st[w][h][t] =
                *(const floatx4*)&sT[sb + (size_t)h * NN_ + w * 256 + t];
    }

    // per-lane s_src for my i-row (row = l16), all heads
    float ssv[4];
#pragma unroll
    for (int h = 0; h < 4; ++h)
        ssv[h] = sS[sb + (size_t)h * NN_ + i0 + l16];

    // adj stage base: rows i0.., cols w*256..
    const float* adj_base = adj + ((size_t)b * NN_ + i0) * NN_ + w * 256;

    floatx4 acc[4][4];                // [head][f-block], 64 regs
#pragma unroll
    for (int h = 0; h < 4; ++h)
#pragma unroll
        for (int K = 0; K < 4; ++K)
            acc[h][K] = (floatx4){0.f, 0.f, 0.f, 0.f};
    float ls[4] = {0.f, 0.f, 0.f, 0.f};

    // prologue: dense-load + stage adj tile jt=0
    floatx4 areg0 = *(const floatx4*)(adj_base + (size_t)r8 * NN_ + c4);
    floatx4 areg1 = *(const floatx4*)(adj_base + (size_t)(8 + r8) * NN_ + c4);
    *(floatx4*)&sm.m.adjs[w][r8][c4]     = areg0;
    *(floatx4*)&sm.m.adjs[w][8 + r8][c4] = areg1;

    const int lo8 = lane * 8;         // PT2 per-lane element offset

#pragma unroll
    for (int jt = 0; jt < 8; ++jt) {              // 8 iters x 32 j per wave
        const int o  = jt * 32;                   // static element offset
        const int qo = quad * 8;

        // T14 issue-early: dense global loads for the NEXT adj tile
        if (jt < 7) {
            areg0 = *(const floatx4*)(adj_base + (size_t)r8 * NN_ + o + 32 + c4);
            areg1 = *(const floatx4*)(adj_base + (size_t)(8 + r8) * NN_ + o + 32 + c4);
        }

        // A-values for this tile from LDS (wave-private, already staged)
        floatx4 ajA = *(const floatx4*)&sm.m.adjs[w][l16][qo];
        floatx4 ajB = *(const floatx4*)&sm.m.adjs[w][l16][qo + 4];

#pragma unroll
        for (int u = 0; u < 4; ++u) {
            // dense 1 KB fragment loads from PT2 (uniform base + lane*16B)
            const short* fb = pt2_b + ((size_t)u * 64 + (w * 8 + jt)) * 2048 + lo8;
            bf16x8 bfr[4];
#pragma unroll
            for (int K = 0; K < 4; ++K)
                bfr[K] = *(const bf16x8*)(fb + K * 512);

            const float* stp = &sm.m.st[w][u][qo];
            floatx4 stA = *(const floatx4*)(stp + o);
            floatx4 stB = *(const floatx4*)(stp + o + 4);

            float w0 = score_exp(ssv[u], stA[0], ajA[0]);
            float w1 = score_exp(ssv[u], stA[1], ajA[1]);
            float w2 = score_exp(ssv[u], stA[2], ajA[2]);
            float w3 = score_exp(ssv[u], stA[3], ajA[3]);
            float w4 = score_exp(ssv[u], stB[0], ajB[0]);
            float w5 = score_exp(ssv[u], stB[1], ajB[1]);
            float w6 = score_exp(ssv[u], stB[2], ajB[2]);
            float w7 = score_exp(ssv[u], stB[3], ajB[3]);
            ls[u] += ((w0 + w1) + (w2 + w3)) + ((w4 + w5) + (w6 + w7));
            union { bf16x8 v; unsigned int u4[4]; } a0;
            a0.u4[0] = pack_bf16(w0, w1);
            a0.u4[1] = pack_bf16(w2, w3);
            a0.u4[2] = pack_bf16(w4, w5);
            a0.u4[3] = pack_bf16(w6, w7);
#pragma unroll
            for (int K = 0; K < 4; ++K)
                acc[u][K] = __builtin_amdgcn_mfma_f32_16x16x32_bf16(
                    a0.v, bfr[K], acc[u][K], 0, 0, 0);
        }

        // T14 write-late: stage next tile after this tile's LDS reads
        if (jt < 7) {
            *(floatx4*)&sm.m.adjs[w][r8][c4]     = areg0;
            *(floatx4*)&sm.m.adjs[w][8 + r8][c4] = areg1;
        }
    }

    // wave-local row-sums over quads (row = l16 in A-layout)
#pragma unroll
    for (int h = 0; h < 4; ++h) {
        ls[h] += __shfl_xor(ls[h], 16, 64);
        ls[h] += __shfl_xor(ls[h], 32, 64);
    }

    // epilogue: 4 head-chunks of 16 rows; 8-wave LDS reduction per chunk
#pragma unroll
    for (int h = 0; h < 4; ++h) {
        __syncthreads();   // h=0: all main-loop LDS reads done; h>0: prev chunk
#pragma unroll
        for (int K = 0; K < 4; ++K)
#pragma unroll
            for (int r = 0; r < 4; ++r)
                sm.red[w][(quad * 4 + r) * RSTRIDE + K * 16 + l16] = acc[h][K][r];
        if (quad == 0)
            sm.red[w][16 * RSTRIDE + l16] = ls[h];
        __syncthreads();
#pragma unroll
        for (int p = 0; p < 2; ++p) {
            int e   = tid + p * 512;
            int row = e >> 6;
            int col = e & 63;
            float s = 0.f, l = 0.f;
#pragma unroll
            for (int ww = 0; ww < 8; ++ww) {
                s += sm.red[ww][row * RSTRIDE + col];
                l += sm.red[ww][16 * RSTRIDE + row];
            }
            float v = s / l + bias[h * FO_ + col];
            v = (v > 0.f) ? v : expm1f(v);        // elu (fp32 out)
            out[((size_t)b * NN_ + i0 + row) * D_ + h * FO_ + col] = v;
        }
    }
}

// ---------------------------------------------------------------------------
// Launch chain (round 9): proj_all -> attn(b0..1) -> copy(stage->ws) ->
// attn(b2..3). Pair-1's ws image is staged inside out[2..3] (4 MB region;
// attn pair-0 never touches it; the copy completes before attn pair-1
// starts overwriting out[2..3]). All values bit-identical to round 8.
// ---------------------------------------------------------------------------
extern "C" void kernel_launch(void* const* d_in, const int* in_sizes, int n_in,
                              void* d_out, int out_size, void* d_ws, size_t ws_size,
                              hipStream_t stream) {
    const float* x     = (const float*)d_in[0];   // (4,2048,128) fp32
    const float* adj   = (const float*)d_in[1];   // (4,2048,2048) fp32
    const float* wproj = (const float*)d_in[2];   // (256,128) fp32
    const float* ssrc  = (const float*)d_in[3];   // (4,64) fp32
    const float* stgt  = (const float*)d_in[4];   // (4,64) fp32
    const float* bias  = (const float*)d_in[5];   // (256,) fp32
    float* out = (float*)d_out;                   // (4,2048,256) fp32

    const size_t SLAB  = (size_t)D_ * NN_ * 2;          // bf16 PT2 (1 MiB)
    const size_t SSLAB = (size_t)2 * H_ * NN_ * 4;      // fp32 sS+sT (64 KiB)
    const size_t PAIR  = 2 * (SLAB + SSLAB);            // 2.125 MiB ws image

    // ws image layout (2 slabs): [PT2 x2][sS x2][sT x2]
    short* pt_ws = (short*)d_ws;
    float* sS_ws = (float*)((char*)d_ws + 2 * SLAB);
    float* sT_ws = sS_ws + 2 * (size_t)H_ * NN_;

    if (ws_size >= PAIR) {
        // staging image: first 2.125 MiB of out's batches 2..3 region (4 MB)
        char* stg = (char*)d_out + (size_t)2 * NN_ * D_ * 4;
        short* pt_st = (short*)stg;
        float* sS_st = (float*)(stg + 2 * SLAB);
        float* sT_st = sS_st + 2 * (size_t)H_ * NN_;

        // 1) all-batch projection (pair0 -> ws, pair1 -> staging)
        proj_kernel<<<dim3(NN_ / 256, H_, BN_), 256, 0, stream>>>(
            x, wproj, ssrc, stgt,
            pt_ws, sS_ws, sT_ws, pt_st, sS_st, sT_st, 0, 2);
        // 2) attention for batches 0..1 (reads ws)
        attn_kernel<<<dim3(NN_ / 16, 1, 2), 512, 0, stream>>>(
            adj, pt_ws, sS_ws, sT_ws, bias, out, 0);
        // 3) bit-exact copy staging -> ws (ws free now)
        copy_kernel<<<dim3(128), 256, 0, stream>>>(
            (floatx4*)d_ws, (const floatx4*)stg, (int)(PAIR / 16));
        // 4) attention for batches 2..3 (reads ws; overwrites staging region)
        attn_kernel<<<dim3(NN_ / 16, 1, 2), 512, 0, stream>>>(
            adj, pt_ws, sS_ws, sT_ws, bias, out, 2);
    } else {
        // fallback: one batch at a time, ws slab 0 only
        float* sS1 = (float*)((char*)d_ws + SLAB);
        float* sT1 = sS1 + (size_t)H_ * NN_;
        for (int b0 = 0; b0 < BN_; ++b0) {
            proj_kernel<<<dim3(NN_ / 256, H_, 1), 256, 0, stream>>>(
                x, wproj, ssrc, stgt,
                pt_ws, sS1, sT1, pt_ws, sS1, sT1, b0, 1);
            attn_kernel<<<dim3(NN_ / 16, 1, 1), 512, 0, stream>>>(
                adj, pt_ws, sS1, sT1, bias, out, b0);
        }
    }
}